// Round 12
// baseline (9411.236 us; speedup 1.0000x reference)
//
#include <hip/hip_runtime.h>

typedef __attribute__((ext_vector_type(8))) short short8;
typedef __attribute__((ext_vector_type(4))) float floatx4;

#define T_STEPS 512
// d_out is FP32: outputs[512][64][1024], ht[64][1024], ct[64][1024]
#define OUT_HT_OFF 33554432ull
#define OUT_CT_OFF 33619968ull

// ws: wxh bf16 [4096][1024] (8MiB) | wxl (8MiB) | hbuf u32 [2][65536] (512KiB) | bar (4KiB)
#define WXH_OFF  0ull
#define WXL_OFF  (8ull << 20)
#define HBUF_OFF (16ull << 20)
#define BAR_OFF  ((16ull << 20) + (512ull << 10))
#define WS_NEED  ((16ull << 20) + (512ull << 10) + 4096ull)

// bar u32 offsets (monotonic, zeroed per call):
//  [xcd*32]      per-XCD arrive counters (L2-local, workgroup-scope RMW only)
//  [256]         global XCD-arrival counter (agent/sc1)
//  [288]         generation = completed steps (agent/sc1)
//  [640+xcd*32]  slot assignment counters (agent/sc1)

static __device__ __forceinline__ unsigned short bf16_rne(float f) {
    union { float f; unsigned int u; } v; v.f = f;
    return (unsigned short)((v.u + 0x7FFFu + ((v.u >> 16) & 1u)) >> 16);
}
static __device__ __forceinline__ float bf16f(unsigned short u) {
    union { unsigned int u; float f; } v; v.u = ((unsigned int)u) << 16;
    return v.f;
}

__global__ void ws_sentinel(float* out) { out[threadIdx.x] = 2.0f; }

// one-time: W fp32 [1024][4096] -> k-major bf16 hi/lo split [4096][1024]
__global__ void __launch_bounds__(256) wsplit(const float* __restrict__ W,
                                              unsigned short* __restrict__ wxh,
                                              unsigned short* __restrict__ wxl) {
    __shared__ float tile[64][65];
    const int tx = threadIdx.x & 63;
    const int ty = threadIdx.x >> 6;
    const int cb = blockIdx.x * 64;
    const int kb = blockIdx.y * 64;
    #pragma unroll
    for (int i = 0; i < 16; ++i) {
        int kl = i * 4 + ty;
        tile[kl][tx] = W[(size_t)(kb + kl) * 4096 + cb + tx];
    }
    __syncthreads();
    #pragma unroll
    for (int i = 0; i < 16; ++i) {
        int cl = i * 4 + ty;
        float v = tile[tx][cl];
        unsigned short hi = bf16_rne(v);
        unsigned short lo = bf16_rne(v - bf16f(hi));
        wxh[(size_t)(cb + cl) * 1024 + kb + tx] = hi;
        wxl[(size_t)(cb + cl) * 1024 + kb + tx] = lo;
    }
}

// persistent LSTM scan. Critical path/step: wait -> stage h (packed u64 sc1
// loads, cheap unpack) -> h.R MFMA (R VGPR-resident, acc seeded with zx[t]) ->
// gates -> pack/store h -> local-L2 arrive. zx[t+1]=x[t+1].W+b runs inside the
// barrier-wait window. Barrier: 32 L2-local RMWs/XCD + 8 global RMWs + gen.
__global__ void __launch_bounds__(256, 1) lstm_scan(
    const float* __restrict__ R,              // [1024][4096] fp32 (resident split)
    const float* __restrict__ bias,           // [4096] fp32
    const float* __restrict__ x,              // [512][64][1024] fp32
    const unsigned short* __restrict__ wxh,   // bf16 [4096][1024] k-major
    const unsigned short* __restrict__ wxl,   // bf16 [4096][1024] k-major
    unsigned* __restrict__ hbuf,              // u32 [2][65536] packed(hi|lo<<16)
    unsigned* __restrict__ bar,
    float* __restrict__ out)                  // fp32 (outputs | ht | ct)
{
    __shared__ __align__(16) char AxH[32768];
    __shared__ __align__(16) char AxL[32768];
    __shared__ __align__(16) char AhH[32768];
    __shared__ __align__(16) char AhL[32768];
    __shared__ float zxl[1024];
    __shared__ unsigned s_as[2];

    const int tid  = threadIdx.x;
    const int lane = tid & 63;
    const int wave = tid >> 6;

    // ---- XCD-aware work assignment ----
    if (tid == 0) {
        unsigned xcc;
        asm volatile("s_getreg_b32 %0, hwreg(HW_REG_XCC_ID)" : "=s"(xcc));
        xcc &= 7u;
        unsigned slot = __hip_atomic_fetch_add(bar + 640 + xcc * 32, 1u,
                            __ATOMIC_RELAXED, __HIP_MEMORY_SCOPE_AGENT);
        s_as[0] = xcc; s_as[1] = slot;
    }
    __syncthreads();
    const int xcd  = (int)s_as[0];
    const int slot = (int)(s_as[1] & 31u);
    const int rg   = slot >> 3;
    const int jg   = xcd * 8 + (slot & 7);    // XCD-local W columns

    const int rowbase = rg * 16;
    const int c16  = lane & 15;
    const int kgrp = lane >> 4;
    const int gate = c16 >> 2;
    const int jj   = c16 & 3;
    const int mycol = gate * 1024 + jg * 16 + wave * 4 + jj;

    // ---- resident R fragments: bf16 hi/lo split (128 VGPR) ----
    short8 rh[32], rl[32];
    #pragma unroll
    for (int kk = 0; kk < 32; ++kk) {
        int kb = kk * 32 + kgrp * 8;
        short8 h8, l8;
        #pragma unroll
        for (int j = 0; j < 8; ++j) {
            float v = R[(size_t)(kb + j) * 4096 + mycol];
            unsigned short hh = bf16_rne(v);
            h8[j] = (short)hh;
            l8[j] = (short)bf16_rne(v - bf16f(hh));
        }
        rh[kk] = h8; rl[kk] = l8;
    }
    const float biasreg = bias[mycol];

    const int erow  = tid >> 4;
    const int eunit = tid & 15;
    const int ew    = eunit >> 2;
    const int ejj   = eunit & 3;
    const int grow  = rowbase + erow;
    const int gcol  = jg * 16 + eunit;
    const size_t cidx = (size_t)grow * 1024 + gcol;
    float c_state = 0.f;

    const int srow = rowbase + c16;
    const int skof = kgrp * 8;

    const unsigned short* bph = wxh + (size_t)mycol * 1024 + kgrp * 8;
    const unsigned short* bpl = wxl + (size_t)mycol * 1024 + kgrp * 8;

    // ---- helper lambda-free macro-ish: stage x[t] from HBM + xW MFMA ----
    // (used in prologue and in each wait window)
    floatx4 zxcur;
    {
        // prologue: stage x[0], compute zx[0]
        #pragma unroll
        for (int q = 0; q < 8; ++q) {
            int kc = wave * 8 + q;
            const float* src = x + (size_t)srow * 1024 + kc * 32 + skof;
            floatx4 f0 = *(const floatx4*)src;
            floatx4 f1 = *(const floatx4*)(src + 4);
            short8 h8, l8;
            #pragma unroll
            for (int j = 0; j < 4; ++j) {
                unsigned short q0 = bf16_rne(f0[j]);
                unsigned short q1 = bf16_rne(f1[j]);
                h8[j] = (short)q0; h8[j + 4] = (short)q1;
                l8[j] = (short)bf16_rne(f0[j] - bf16f(q0));
                l8[j + 4] = (short)bf16_rne(f1[j] - bf16f(q1));
            }
            *(short8*)(AxH + kc * 1024 + lane * 16) = h8;
            *(short8*)(AxL + kc * 1024 + lane * 16) = l8;
        }
        __syncthreads();
        floatx4 b0 = {0,0,0,0}, b1 = {0,0,0,0}, b2 = {0,0,0,0}, b3 = {0,0,0,0};
        #pragma unroll
        for (int kk = 0; kk < 32; ++kk) {
            short8 bxh = *(const short8*)(bph + kk * 32);
            short8 bxl = *(const short8*)(bpl + kk * 32);
            short8 axh = *(const short8*)(AxH + kk * 1024 + lane * 16);
            short8 axl = *(const short8*)(AxL + kk * 1024 + lane * 16);
            b0 = __builtin_amdgcn_mfma_f32_16x16x32_bf16(axh, bxh, b0, 0, 0, 0);
            b1 = __builtin_amdgcn_mfma_f32_16x16x32_bf16(axh, bxl, b1, 0, 0, 0);
            b2 = __builtin_amdgcn_mfma_f32_16x16x32_bf16(axl, bxh, b2, 0, 0, 0);
            b3 = __builtin_amdgcn_mfma_f32_16x16x32_bf16(axl, bxl, b3, 0, 0, 0);
        }
        #pragma unroll
        for (int i = 0; i < 4; ++i)
            zxcur[i] = ((b0[i] + b1[i]) + (b2[i] + b3[i])) + biasreg;
        __syncthreads();   // AxH/AxL free for next staging
    }

    for (int t = 0; t < T_STEPS; ++t) {
        const bool more = (t + 1 < T_STEPS);

        // ---- stage h_{t-1} from packed hbuf (sc1 u64 loads, cheap unpack) ----
        const unsigned long long* hp64 = (const unsigned long long*)
            (hbuf + (size_t)(t & 1) * 65536) + ((size_t)srow * 512);
        #pragma unroll
        for (int q = 0; q < 8; ++q) {
            int kc = wave * 8 + q;
            short8 h8 = {0,0,0,0,0,0,0,0};
            short8 l8 = {0,0,0,0,0,0,0,0};
            if (t > 0) {
                const unsigned long long* p = hp64 + kc * 16 + kgrp * 4;
                #pragma unroll
                for (int j2 = 0; j2 < 4; ++j2) {
                    unsigned long long u = __hip_atomic_load(p + j2,
                        __ATOMIC_RELAXED, __HIP_MEMORY_SCOPE_AGENT);
                    h8[2 * j2]     = (short)(u & 0xffffu);
                    l8[2 * j2]     = (short)((u >> 16) & 0xffffu);
                    h8[2 * j2 + 1] = (short)((u >> 32) & 0xffffu);
                    l8[2 * j2 + 1] = (short)(u >> 48);
                }
            }
            *(short8*)(AhH + kc * 1024 + lane * 16) = h8;
            *(short8*)(AhL + kc * 1024 + lane * 16) = l8;
        }
        __syncthreads();

        // ---- h.R MFMA, acc seeded with zx[t] (R resident) ----
        floatx4 a0 = zxcur;
        floatx4 a1 = {0,0,0,0}, a2 = {0,0,0,0}, a3 = {0,0,0,0};
        #pragma unroll
        for (int kk = 0; kk < 32; ++kk) {
            short8 ahh = *(const short8*)(AhH + kk * 1024 + lane * 16);
            short8 ahl = *(const short8*)(AhL + kk * 1024 + lane * 16);
            a0 = __builtin_amdgcn_mfma_f32_16x16x32_bf16(ahh, rh[kk], a0, 0, 0, 0);
            a1 = __builtin_amdgcn_mfma_f32_16x16x32_bf16(ahh, rl[kk], a1, 0, 0, 0);
            a2 = __builtin_amdgcn_mfma_f32_16x16x32_bf16(ahl, rh[kk], a2, 0, 0, 0);
            a3 = __builtin_amdgcn_mfma_f32_16x16x32_bf16(ahl, rl[kk], a3, 0, 0, 0);
        }

        // ---- z exchange ----
        #pragma unroll
        for (int i = 0; i < 4; ++i) {
            float z = (a0[i] + a1[i]) + (a2[i] + a3[i]);   // bias already in seed
            zxl[wave * 256 + (kgrp * 4 + i) * 16 + c16] = z;
        }
        __syncthreads();

        // ---- gates + state; pack h; store h (sc1 u64) + out (plain) ----
        {
            float zi = zxl[ew * 256 + erow * 16 +  0 + ejj];
            float zf = zxl[ew * 256 + erow * 16 +  4 + ejj];
            float zc = zxl[ew * 256 + erow * 16 +  8 + ejj];
            float zo = zxl[ew * 256 + erow * 16 + 12 + ejj];
            float ig = 1.0f / (1.0f + expf(-zi));
            float fg = 1.0f / (1.0f + expf(-zf));
            float og = 1.0f / (1.0f + expf(-zo));
            float cc = tanhf(zc);
            float cn = fg * c_state + ig * cc;
            c_state = cn;
            float hval = og * tanhf(cn);

            out[(size_t)t * 65536 + cidx] = hval;
            if (more) {
                unsigned short hi = bf16_rne(hval);
                unsigned short lo = bf16_rne(hval - bf16f(hi));
                unsigned hp = (unsigned)hi | ((unsigned)lo << 16);
                unsigned hq = (unsigned)__shfl_xor((int)hp, 1, 64);
                if (!(lane & 1)) {
                    unsigned long long u = (unsigned long long)hp
                                         | ((unsigned long long)hq << 32);
                    __hip_atomic_store((unsigned long long*)
                        (hbuf + (size_t)((t + 1) & 1) * 65536) + (cidx >> 1), u,
                        __ATOMIC_RELAXED, __HIP_MEMORY_SCOPE_AGENT);
                }
            } else {
                out[OUT_HT_OFF + cidx] = hval;
                out[OUT_CT_OFF + cidx] = cn;
            }
        }
        __syncthreads();   // all h stores drained (vmcnt0) before arrive

        if (more) {
            // ---- arrive: L2-local per-XCD, then 8 global RMWs ----
            if (tid == 0) {
                unsigned s = (unsigned)(t + 1);
                unsigned old = __hip_atomic_fetch_add(bar + xcd * 32, 1u,
                                  __ATOMIC_RELAXED, __HIP_MEMORY_SCOPE_WORKGROUP);
                if (old == s * 32u - 1u) {
                    unsigned og = __hip_atomic_fetch_add(bar + 256, 1u,
                                      __ATOMIC_RELAXED, __HIP_MEMORY_SCOPE_AGENT);
                    if (og == s * 8u - 1u) {
                        __hip_atomic_store(bar + 288, s,
                                           __ATOMIC_RELAXED, __HIP_MEMORY_SCOPE_AGENT);
                    }
                }
            }

            // ---- window: stage x[t+1] (HBM) + xW MFMA -> zx[t+1] ----
            #pragma unroll
            for (int q = 0; q < 8; ++q) {
                int kc = wave * 8 + q;
                const float* src = x + (size_t)(t + 1) * 65536
                                     + (size_t)srow * 1024 + kc * 32 + skof;
                floatx4 f0 = *(const floatx4*)src;
                floatx4 f1 = *(const floatx4*)(src + 4);
                short8 h8, l8;
                #pragma unroll
                for (int j = 0; j < 4; ++j) {
                    unsigned short q0 = bf16_rne(f0[j]);
                    unsigned short q1 = bf16_rne(f1[j]);
                    h8[j] = (short)q0; h8[j + 4] = (short)q1;
                    l8[j] = (short)bf16_rne(f0[j] - bf16f(q0));
                    l8[j + 4] = (short)bf16_rne(f1[j] - bf16f(q1));
                }
                *(short8*)(AxH + kc * 1024 + lane * 16) = h8;
                *(short8*)(AxL + kc * 1024 + lane * 16) = l8;
            }
            __syncthreads();
            floatx4 b0 = {0,0,0,0}, b1 = {0,0,0,0}, b2 = {0,0,0,0}, b3 = {0,0,0,0};
            #pragma unroll
            for (int kk = 0; kk < 32; ++kk) {
                short8 bxh = *(const short8*)(bph + kk * 32);
                short8 bxl = *(const short8*)(bpl + kk * 32);
                short8 axh = *(const short8*)(AxH + kk * 1024 + lane * 16);
                short8 axl = *(const short8*)(AxL + kk * 1024 + lane * 16);
                b0 = __builtin_amdgcn_mfma_f32_16x16x32_bf16(axh, bxh, b0, 0, 0, 0);
                b1 = __builtin_amdgcn_mfma_f32_16x16x32_bf16(axh, bxl, b1, 0, 0, 0);
                b2 = __builtin_amdgcn_mfma_f32_16x16x32_bf16(axl, bxh, b2, 0, 0, 0);
                b3 = __builtin_amdgcn_mfma_f32_16x16x32_bf16(axl, bxl, b3, 0, 0, 0);
            }
            #pragma unroll
            for (int i = 0; i < 4; ++i)
                zxcur[i] = ((b0[i] + b1[i]) + (b2[i] + b3[i])) + biasreg;

            // ---- wait for step completion ----
            if (tid == 0) {
                while (__hip_atomic_load(bar + 288, __ATOMIC_RELAXED,
                                         __HIP_MEMORY_SCOPE_AGENT) < (unsigned)(t + 1)) {
                    __builtin_amdgcn_s_sleep(4);
                }
            }
            __syncthreads();
        }
    }
}

extern "C" void kernel_launch(void* const* d_in, const int* in_sizes, int n_in,
                              void* d_out, int out_size, void* d_ws, size_t ws_size,
                              hipStream_t stream) {
    const float* inputs = (const float*)d_in[0];
    const float* W      = (const float*)d_in[1];
    const float* R      = (const float*)d_in[2];
    const float* bias   = (const float*)d_in[3];
    float* out = (float*)d_out;

    if (ws_size < WS_NEED) {
        ws_sentinel<<<1, 64, 0, stream>>>(out);
        return;
    }

    unsigned short* wxh  = (unsigned short*)((char*)d_ws + WXH_OFF);
    unsigned short* wxl  = (unsigned short*)((char*)d_ws + WXL_OFF);
    unsigned*       hbuf = (unsigned*)((char*)d_ws + HBUF_OFF);
    unsigned*       bar  = (unsigned*)((char*)d_ws + BAR_OFF);

    hipMemsetAsync(bar, 0, 4096, stream);
    wsplit<<<dim3(64, 16), 256, 0, stream>>>(W, wxh, wxl);
    lstm_scan<<<256, 256, 0, stream>>>(R, bias, inputs, wxh, wxl, hbuf, bar, out);
}

// Round 13
// 9014.485 us; speedup vs baseline: 1.0440x; 1.0440x over previous
//
#include <hip/hip_runtime.h>

typedef __attribute__((ext_vector_type(8))) short short8;
typedef __attribute__((ext_vector_type(4))) float floatx4;
typedef __attribute__((ext_vector_type(4))) int intx4;

#define T_STEPS 512
// d_out is FP32: outputs[512][64][1024], ht[64][1024], ct[64][1024]
#define OUT_HT_OFF 33554432ull
#define OUT_CT_OFF 33619968ull

// ws: wxh bf16 [4096][1024] (8MiB) | wxl (8MiB) | hbuf u32 [2][65536] (512KiB) | bar (4KiB)
#define WXH_OFF  0ull
#define WXL_OFF  (8ull << 20)
#define HBUF_OFF (16ull << 20)
#define BAR_OFF  ((16ull << 20) + (512ull << 10))
#define WS_NEED  ((16ull << 20) + (512ull << 10) + 4096ull)

// bar u32 offsets: [xcd*32] per-XCD arrive (L2-local) | [256] XCD-arrival |
// [288] generation | [640+xcd*32] slot assignment

static __device__ __forceinline__ unsigned short bf16_rne(float f) {
    union { float f; unsigned int u; } v; v.f = f;
    return (unsigned short)((v.u + 0x7FFFu + ((v.u >> 16) & 1u)) >> 16);
}
static __device__ __forceinline__ float bf16f(unsigned short u) {
    union { unsigned int u; float f; } v; v.u = ((unsigned int)u) << 16;
    return v.f;
}

__global__ void ws_sentinel(float* out) { out[threadIdx.x] = 2.0f; }

// one-time: W fp32 [1024][4096] -> k-major bf16 hi/lo split [4096][1024]
__global__ void __launch_bounds__(256) wsplit(const float* __restrict__ W,
                                              unsigned short* __restrict__ wxh,
                                              unsigned short* __restrict__ wxl) {
    __shared__ float tile[64][65];
    const int tx = threadIdx.x & 63;
    const int ty = threadIdx.x >> 6;
    const int cb = blockIdx.x * 64;
    const int kb = blockIdx.y * 64;
    #pragma unroll
    for (int i = 0; i < 16; ++i) {
        int kl = i * 4 + ty;
        tile[kl][tx] = W[(size_t)(kb + kl) * 4096 + cb + tx];
    }
    __syncthreads();
    #pragma unroll
    for (int i = 0; i < 16; ++i) {
        int cl = i * 4 + ty;
        float v = tile[tx][cl];
        unsigned short hi = bf16_rne(v);
        unsigned short lo = bf16_rne(v - bf16f(hi));
        wxh[(size_t)(cb + cl) * 1024 + kb + tx] = hi;
        wxl[(size_t)(cb + cl) * 1024 + kb + tx] = lo;
    }
}

// batched device-coherent h load (non-atomic, pipelined)
#define HLOAD(dst, OFF) \
    asm volatile("global_load_dwordx4 %0, %1, off offset:" OFF " sc0 sc1" \
                 : "=v"(dst) : "v"(hp8) : "memory");

// progressive wait + unpack chunk q from two dwordx4 (8 packed u32 -> hi/lo bf16)
#define HSTAGE(q, ra, rb, WAITSTR) \
    asm volatile("s_waitcnt " WAITSTR ::: "memory"); \
    __builtin_amdgcn_sched_barrier(0); \
    { unsigned w0=(unsigned)(ra).x, w1=(unsigned)(ra).y, w2=(unsigned)(ra).z, w3=(unsigned)(ra).w; \
      unsigned v0=(unsigned)(rb).x, v1=(unsigned)(rb).y, v2=(unsigned)(rb).z, v3=(unsigned)(rb).w; \
      intx4 hh, ll; \
      hh.x=(int)((w0&0xffffu)|(w1<<16)); hh.y=(int)((w2&0xffffu)|(w3<<16)); \
      hh.z=(int)((v0&0xffffu)|(v1<<16)); hh.w=(int)((v2&0xffffu)|(v3<<16)); \
      ll.x=(int)((w0>>16)|(w1&0xffff0000u)); ll.y=(int)((w2>>16)|(w3&0xffff0000u)); \
      ll.z=(int)((v0>>16)|(v1&0xffff0000u)); ll.w=(int)((v2>>16)|(v3&0xffff0000u)); \
      *(intx4*)(AhH + (wave*8+(q))*1024 + lane*16) = hh; \
      *(intx4*)(AhL + (wave*8+(q))*1024 + lane*16) = ll; }

__global__ void __launch_bounds__(256, 1) lstm_scan(
    const float* __restrict__ R,              // [1024][4096] fp32 (resident split)
    const float* __restrict__ bias,           // [4096] fp32
    const float* __restrict__ x,              // [512][64][1024] fp32
    const unsigned short* __restrict__ wxh,   // bf16 [4096][1024] k-major
    const unsigned short* __restrict__ wxl,   // bf16 [4096][1024] k-major
    unsigned* __restrict__ hbuf,              // u32 [2][65536] packed(hi|lo<<16)
    unsigned* __restrict__ bar,
    float* __restrict__ out)                  // fp32 (outputs | ht | ct)
{
    __shared__ __align__(16) char AxH[32768];
    __shared__ __align__(16) char AxL[32768];
    __shared__ __align__(16) char AhH[32768];
    __shared__ __align__(16) char AhL[32768];
    __shared__ float zxl[1024];
    __shared__ unsigned s_as[2];

    const int tid  = threadIdx.x;
    const int lane = tid & 63;
    const int wave = tid >> 6;

    // ---- XCD-aware work assignment ----
    if (tid == 0) {
        unsigned xcc;
        asm volatile("s_getreg_b32 %0, hwreg(HW_REG_XCC_ID)" : "=s"(xcc));
        xcc &= 7u;
        unsigned slot = __hip_atomic_fetch_add(bar + 640 + xcc * 32, 1u,
                            __ATOMIC_RELAXED, __HIP_MEMORY_SCOPE_AGENT);
        s_as[0] = xcc; s_as[1] = slot;
    }
    __syncthreads();
    const int xcd  = (int)s_as[0];
    const int slot = (int)(s_as[1] & 31u);
    const int rg   = slot >> 3;
    const int jg   = xcd * 8 + (slot & 7);    // XCD-local W columns

    const int rowbase = rg * 16;
    const int c16  = lane & 15;
    const int kgrp = lane >> 4;
    const int gate = c16 >> 2;
    const int jj   = c16 & 3;
    const int mycol = gate * 1024 + jg * 16 + wave * 4 + jj;

    // ---- resident R fragments: bf16 hi/lo split ----
    short8 rh[32], rl[32];
    #pragma unroll
    for (int kk = 0; kk < 32; ++kk) {
        int kb = kk * 32 + kgrp * 8;
        short8 h8, l8;
        #pragma unroll
        for (int j = 0; j < 8; ++j) {
            float v = R[(size_t)(kb + j) * 4096 + mycol];
            unsigned short hh = bf16_rne(v);
            h8[j] = (short)hh;
            l8[j] = (short)bf16_rne(v - bf16f(hh));
        }
        rh[kk] = h8; rl[kk] = l8;
    }
    const float biasreg = bias[mycol];

    const int erow  = tid >> 4;
    const int eunit = tid & 15;
    const int ew    = eunit >> 2;
    const int ejj   = eunit & 3;
    const int grow  = rowbase + erow;
    const int gcol  = jg * 16 + eunit;
    const size_t cidx = (size_t)grow * 1024 + gcol;
    float c_state = 0.f;

    const int srow = rowbase + c16;
    const int skof = kgrp * 8;

    const unsigned short* bph = wxh + (size_t)mycol * 1024 + kgrp * 8;
    const unsigned short* bpl = wxl + (size_t)mycol * 1024 + kgrp * 8;

    // ---- prologue: stage x[0], compute zx[0] ----
    floatx4 zxcur;
    {
        #pragma unroll
        for (int q = 0; q < 8; ++q) {
            int kc = wave * 8 + q;
            const float* src = x + (size_t)srow * 1024 + kc * 32 + skof;
            floatx4 f0 = *(const floatx4*)src;
            floatx4 f1 = *(const floatx4*)(src + 4);
            short8 h8, l8;
            #pragma unroll
            for (int j = 0; j < 4; ++j) {
                unsigned short q0 = bf16_rne(f0[j]);
                unsigned short q1 = bf16_rne(f1[j]);
                h8[j] = (short)q0; h8[j + 4] = (short)q1;
                l8[j] = (short)bf16_rne(f0[j] - bf16f(q0));
                l8[j + 4] = (short)bf16_rne(f1[j] - bf16f(q1));
            }
            *(short8*)(AxH + kc * 1024 + lane * 16) = h8;
            *(short8*)(AxL + kc * 1024 + lane * 16) = l8;
        }
        __syncthreads();
        floatx4 b0 = {0,0,0,0}, b1 = {0,0,0,0}, b2 = {0,0,0,0}, b3 = {0,0,0,0};
        #pragma unroll
        for (int kk = 0; kk < 32; ++kk) {
            short8 bxh = *(const short8*)(bph + kk * 32);
            short8 bxl = *(const short8*)(bpl + kk * 32);
            short8 axh = *(const short8*)(AxH + kk * 1024 + lane * 16);
            short8 axl = *(const short8*)(AxL + kk * 1024 + lane * 16);
            b0 = __builtin_amdgcn_mfma_f32_16x16x32_bf16(axh, bxh, b0, 0, 0, 0);
            b1 = __builtin_amdgcn_mfma_f32_16x16x32_bf16(axh, bxl, b1, 0, 0, 0);
            b2 = __builtin_amdgcn_mfma_f32_16x16x32_bf16(axl, bxh, b2, 0, 0, 0);
            b3 = __builtin_amdgcn_mfma_f32_16x16x32_bf16(axl, bxl, b3, 0, 0, 0);
        }
        #pragma unroll
        for (int i = 0; i < 4; ++i)
            zxcur[i] = ((b0[i] + b1[i]) + (b2[i] + b3[i])) + biasreg;
        __syncthreads();
    }

    for (int t = 0; t < T_STEPS; ++t) {
        const bool more = (t + 1 < T_STEPS);

        // ---- stage h_{t-1}: 16 pipelined sc0sc1 loads, counted waits ----
        if (t > 0) {
            const char* hp8 = (const char*)(hbuf + (size_t)(t & 1) * 65536)
                            + srow * 4096 + wave * 1024 + kgrp * 32;
            intx4 r0, r1, r2, r3, r4, r5, r6, r7;
            intx4 r8, r9, r10, r11, r12, r13, r14, r15;
            HLOAD(r0,  "0")   HLOAD(r1,  "16")
            HLOAD(r2,  "128") HLOAD(r3,  "144")
            HLOAD(r4,  "256") HLOAD(r5,  "272")
            HLOAD(r6,  "384") HLOAD(r7,  "400")
            HLOAD(r8,  "512") HLOAD(r9,  "528")
            HLOAD(r10, "640") HLOAD(r11, "656")
            HLOAD(r12, "768") HLOAD(r13, "784")
            HLOAD(r14, "896") HLOAD(r15, "912")
            HSTAGE(0, r0,  r1,  "vmcnt(14)")
            HSTAGE(1, r2,  r3,  "vmcnt(12)")
            HSTAGE(2, r4,  r5,  "vmcnt(10)")
            HSTAGE(3, r6,  r7,  "vmcnt(8)")
            HSTAGE(4, r8,  r9,  "vmcnt(6)")
            HSTAGE(5, r10, r11, "vmcnt(4)")
            HSTAGE(6, r12, r13, "vmcnt(2)")
            HSTAGE(7, r14, r15, "vmcnt(0)")
        } else {
            intx4 z4 = {0, 0, 0, 0};
            #pragma unroll
            for (int q = 0; q < 8; ++q) {
                *(intx4*)(AhH + (wave * 8 + q) * 1024 + lane * 16) = z4;
                *(intx4*)(AhL + (wave * 8 + q) * 1024 + lane * 16) = z4;
            }
        }
        __syncthreads();

        // ---- h.R MFMA, acc seeded with zx[t] (R resident) ----
        floatx4 a0 = zxcur;
        floatx4 a1 = {0,0,0,0}, a2 = {0,0,0,0}, a3 = {0,0,0,0};
        #pragma unroll
        for (int kk = 0; kk < 32; ++kk) {
            short8 ahh = *(const short8*)(AhH + kk * 1024 + lane * 16);
            short8 ahl = *(const short8*)(AhL + kk * 1024 + lane * 16);
            a0 = __builtin_amdgcn_mfma_f32_16x16x32_bf16(ahh, rh[kk], a0, 0, 0, 0);
            a1 = __builtin_amdgcn_mfma_f32_16x16x32_bf16(ahh, rl[kk], a1, 0, 0, 0);
            a2 = __builtin_amdgcn_mfma_f32_16x16x32_bf16(ahl, rh[kk], a2, 0, 0, 0);
            a3 = __builtin_amdgcn_mfma_f32_16x16x32_bf16(ahl, rl[kk], a3, 0, 0, 0);
        }

        // ---- z exchange ----
        #pragma unroll
        for (int i = 0; i < 4; ++i) {
            float z = (a0[i] + a1[i]) + (a2[i] + a3[i]);
            zxl[wave * 256 + (kgrp * 4 + i) * 16 + c16] = z;
        }
        __syncthreads();

        // ---- gates + state; h -> packed sc0sc1 store + plain out store ----
        {
            float zi = zxl[ew * 256 + erow * 16 +  0 + ejj];
            float zf = zxl[ew * 256 + erow * 16 +  4 + ejj];
            float zc = zxl[ew * 256 + erow * 16 +  8 + ejj];
            float zo = zxl[ew * 256 + erow * 16 + 12 + ejj];
            float ig = 1.0f / (1.0f + expf(-zi));
            float fg = 1.0f / (1.0f + expf(-zf));
            float og = 1.0f / (1.0f + expf(-zo));
            float cc = tanhf(zc);
            float cn = fg * c_state + ig * cc;
            c_state = cn;
            float hval = og * tanhf(cn);

            out[(size_t)t * 65536 + cidx] = hval;
            if (more) {
                unsigned short hi = bf16_rne(hval);
                unsigned short lo = bf16_rne(hval - bf16f(hi));
                unsigned w = (unsigned)hi | ((unsigned)lo << 16);
                unsigned* dst = hbuf + (size_t)((t + 1) & 1) * 65536 + cidx;
                asm volatile("global_store_dword %0, %1, off sc0 sc1"
                             :: "v"(dst), "v"(w) : "memory");
            } else {
                out[OUT_HT_OFF + cidx] = hval;
                out[OUT_CT_OFF + cidx] = cn;
            }
        }
        asm volatile("s_waitcnt vmcnt(0)" ::: "memory");   // h stores at MALL
        __syncthreads();

        if (more) {
            // ---- arrive: L2-local per-XCD, then 8 global RMWs ----
            if (tid == 0) {
                unsigned s = (unsigned)(t + 1);
                unsigned old = __hip_atomic_fetch_add(bar + xcd * 32, 1u,
                                  __ATOMIC_RELAXED, __HIP_MEMORY_SCOPE_WORKGROUP);
                if (old == s * 32u - 1u) {
                    unsigned og = __hip_atomic_fetch_add(bar + 256, 1u,
                                      __ATOMIC_RELAXED, __HIP_MEMORY_SCOPE_AGENT);
                    if (og == s * 8u - 1u) {
                        __hip_atomic_store(bar + 288, s,
                                           __ATOMIC_RELAXED, __HIP_MEMORY_SCOPE_AGENT);
                    }
                }
            }

            // ---- window: stage x[t+1] + xW MFMA -> zx[t+1] ----
            #pragma unroll
            for (int q = 0; q < 8; ++q) {
                int kc = wave * 8 + q;
                const float* src = x + (size_t)(t + 1) * 65536
                                     + (size_t)srow * 1024 + kc * 32 + skof;
                floatx4 f0 = *(const floatx4*)src;
                floatx4 f1 = *(const floatx4*)(src + 4);
                short8 h8, l8;
                #pragma unroll
                for (int j = 0; j < 4; ++j) {
                    unsigned short q0 = bf16_rne(f0[j]);
                    unsigned short q1 = bf16_rne(f1[j]);
                    h8[j] = (short)q0; h8[j + 4] = (short)q1;
                    l8[j] = (short)bf16_rne(f0[j] - bf16f(q0));
                    l8[j + 4] = (short)bf16_rne(f1[j] - bf16f(q1));
                }
                *(short8*)(AxH + kc * 1024 + lane * 16) = h8;
                *(short8*)(AxL + kc * 1024 + lane * 16) = l8;
            }
            __syncthreads();
            floatx4 b0 = {0,0,0,0}, b1 = {0,0,0,0}, b2 = {0,0,0,0}, b3 = {0,0,0,0};
            #pragma unroll
            for (int kk = 0; kk < 32; ++kk) {
                short8 bxh = *(const short8*)(bph + kk * 32);
                short8 bxl = *(const short8*)(bpl + kk * 32);
                short8 axh = *(const short8*)(AxH + kk * 1024 + lane * 16);
                short8 axl = *(const short8*)(AxL + kk * 1024 + lane * 16);
                b0 = __builtin_amdgcn_mfma_f32_16x16x32_bf16(axh, bxh, b0, 0, 0, 0);
                b1 = __builtin_amdgcn_mfma_f32_16x16x32_bf16(axh, bxl, b1, 0, 0, 0);
                b2 = __builtin_amdgcn_mfma_f32_16x16x32_bf16(axl, bxh, b2, 0, 0, 0);
                b3 = __builtin_amdgcn_mfma_f32_16x16x32_bf16(axl, bxl, b3, 0, 0, 0);
            }
            #pragma unroll
            for (int i = 0; i < 4; ++i)
                zxcur[i] = ((b0[i] + b1[i]) + (b2[i] + b3[i])) + biasreg;

            // ---- wait for step completion ----
            if (tid == 0) {
                while (__hip_atomic_load(bar + 288, __ATOMIC_RELAXED,
                                         __HIP_MEMORY_SCOPE_AGENT) < (unsigned)(t + 1)) {
                    __builtin_amdgcn_s_sleep(2);
                }
            }
            __syncthreads();
        }
    }
}

extern "C" void kernel_launch(void* const* d_in, const int* in_sizes, int n_in,
                              void* d_out, int out_size, void* d_ws, size_t ws_size,
                              hipStream_t stream) {
    const float* inputs = (const float*)d_in[0];
    const float* W      = (const float*)d_in[1];
    const float* R      = (const float*)d_in[2];
    const float* bias   = (const float*)d_in[3];
    float* out = (float*)d_out;

    if (ws_size < WS_NEED) {
        ws_sentinel<<<1, 64, 0, stream>>>(out);
        return;
    }

    unsigned short* wxh  = (unsigned short*)((char*)d_ws + WXH_OFF);
    unsigned short* wxl  = (unsigned short*)((char*)d_ws + WXL_OFF);
    unsigned*       hbuf = (unsigned*)((char*)d_ws + HBUF_OFF);
    unsigned*       bar  = (unsigned*)((char*)d_ws + BAR_OFF);

    hipMemsetAsync(bar, 0, 4096, stream);
    wsplit<<<dim3(64, 16), 256, 0, stream>>>(W, wxh, wxl);
    lstm_scan<<<256, 256, 0, stream>>>(R, bias, inputs, wxh, wxl, hbuf, bar, out);
}